// Round 1
// baseline (16264.052 us; speedup 1.0000x reference)
//
#include <hip/hip_runtime.h>
#include <math.h>

// WaveNet forward, f32 baseline (round 1: correctness + compute-bound structure).
// N=4, W=16384, C=128 (res/chans), S=256 (skip/2*res), 30 layers, kernel=2.
//
// Structure:
//   prep:   transpose weights to [in][out] so weight loads are wave-uniform (s_load)
//   front:  h0[n,c,t] = w0[c]*x[t-2] + w1[c]*x[t-1] + b[c]
//   layer x30 (ping-pong h in ws): conv(2 taps, dilated) -> GLU -> res += h, skip
//           accumulated straight into d_out (d_out is exactly (N,256,W) f32)
//   final:  in-place on d_out: relu -> a_w matmul -> relu -> b_w matmul
//
// ws budget: 2*h (2*33.55MB) + transposed weights (~14MB) ~= 81.4 MB.

#define NB 4
#define WLEN 16384
#define C 128
#define S 256
#define NLAYERS 30
#define TT 64

__device__ __forceinline__ float sigmoidf_(float v) {
    return 1.0f / (1.0f + __expf(-v));
}

// ---------------- weight transpose ----------------
// convT[l][k][i][o] = conv_w[l][o][i][k]        (30*2*128*256)
// resT [l][r][c]    = res_w [l][c][r]           (30*128*128)
// skipT[l][r][o]    = skip_w[l][o][r]           (30*128*256)
// aT   [s][o]       = a_w   [o][s]              (256*256)
// bT   [e][o]       = b_w   [o][e]              (256*256)
__global__ void prep_kernel(const float* __restrict__ conv_w,
                            const float* __restrict__ res_w,
                            const float* __restrict__ skip_w,
                            const float* __restrict__ a_w,
                            const float* __restrict__ b_w,
                            float* __restrict__ convT,
                            float* __restrict__ resT,
                            float* __restrict__ skipT,
                            float* __restrict__ aT,
                            float* __restrict__ bT) {
    const int czs = NLAYERS * 2 * C * S;
    const int rzs = NLAYERS * C * C;
    const int szs = NLAYERS * C * S;
    const int azs = 256 * 256;
    const int total = czs + rzs + szs + azs + azs;
    for (int idx = blockIdx.x * blockDim.x + threadIdx.x; idx < total;
         idx += gridDim.x * blockDim.x) {
        int i = idx;
        if (i < czs) {
            int o = i % S; int r = i / S;
            int ci = r % C; r /= C;
            int k = r % 2; int l = r / 2;
            convT[i] = conv_w[((l * S + o) * C + ci) * 2 + k];
        } else if (i < czs + rzs) {
            i -= czs;
            int c = i % C; int r = i / C;
            int rr = r % C; int l = r / C;
            resT[i] = res_w[(l * C + c) * C + rr];
        } else if (i < czs + rzs + szs) {
            i -= czs + rzs;
            int o = i % S; int r = i / S;
            int rr = r % C; int l = r / C;
            skipT[i] = skip_w[(l * S + o) * C + rr];
        } else if (i < czs + rzs + szs + azs) {
            i -= czs + rzs + szs;
            int o = i % 256; int s = i / 256;
            aT[i] = a_w[o * 256 + s];
        } else {
            i -= czs + rzs + szs + azs;
            int o = i % 256; int e = i / 256;
            bT[i] = b_w[o * 256 + e];
        }
    }
}

// ---------------- front (shifted causal conv, k=2, dil=1) ----------------
// h[n,c,t] = w_shift[c,0]*x[n,t-2] + w_shift[c,1]*x[n,t-1] + b_shift[c]
__global__ void front_kernel(const float* __restrict__ x,
                             const float* __restrict__ w_shift,
                             const float* __restrict__ b_shift,
                             float* __restrict__ h) {
    const int n = blockIdx.y;
    const int t = blockIdx.x * 256 + threadIdx.x;
    float x1 = (t >= 1) ? x[n * WLEN + t - 1] : 0.0f;
    float x2 = (t >= 2) ? x[n * WLEN + t - 2] : 0.0f;
    #pragma unroll 4
    for (int c = 0; c < C; ++c) {
        float v = fmaf(w_shift[2 * c], x2, fmaf(w_shift[2 * c + 1], x1, b_shift[c]));
        h[(n * C + c) * WLEN + t] = v;
    }
}

// ---------------- one residual layer ----------------
// Block: 256 threads = 4 waves; lane = t within 64-wide tile; wave = output group.
// LDS 64KB (g then gated) -> 2 blocks/CU.
template <bool FIRST>
__global__ __launch_bounds__(256, 2) void layer_kernel(
    const float* __restrict__ h_in, float* __restrict__ h_out,
    float* __restrict__ skips,
    const float* __restrict__ convT, const float* __restrict__ convb,
    const float* __restrict__ resT, const float* __restrict__ resb,
    const float* __restrict__ skipT, const float* __restrict__ skipb,
    int d) {
    __shared__ float lds[S * TT];  // 64 KB: g[256][64] then gated[128][64]
    const int n = blockIdx.y;
    const int t0 = blockIdx.x * TT;
    const int wave = __builtin_amdgcn_readfirstlane(threadIdx.x >> 6);
    const int lane = threadIdx.x & 63;
    const int t = t0 + lane;
    const int obase = wave * 64;

    // Phase 1: dilated conv, 64 output channels per wave, acc in VGPRs.
    float g[64];
    #pragma unroll
    for (int o = 0; o < 64; ++o) g[o] = convb[obase + o];

    const float* hin_n = h_in + (size_t)n * C * WLEN;
    const int tb = t - d;
    for (int i = 0; i < C; ++i) {
        float hA = hin_n[i * WLEN + t];                       // tap k=1 (current)
        float hB = (tb >= 0) ? hin_n[i * WLEN + tb] : 0.0f;   // tap k=0 (t-d)
        const float* w0 = convT + i * S + obase;              // k=0 weights
        const float* w1 = convT + C * S + i * S + obase;      // k=1 weights
        #pragma unroll
        for (int o = 0; o < 64; ++o) {
            g[o] = fmaf(w0[o], hB, g[o]);
            g[o] = fmaf(w1[o], hA, g[o]);
        }
    }
    #pragma unroll
    for (int o = 0; o < 64; ++o) lds[(obase + o) * TT + lane] = g[o];
    __syncthreads();

    // Phase 2: GLU. gated[r][t] = g[r][t] * sigmoid(g[r+128][t]), in-place low half.
    #pragma unroll
    for (int j = 0; j < 32; ++j) {
        int flat = j * 256 + threadIdx.x;  // [0, 128*64)
        float a = lds[flat];
        float b = lds[flat + C * TT];
        lds[flat] = a * sigmoidf_(b);
    }
    __syncthreads();

    // Phase 3: res (32 ch/wave) + skip (64 ch/wave) matmuls over r=0..127.
    const int cbase = wave * 32;
    float racc[32];
    float sacc[64];
    #pragma unroll
    for (int j = 0; j < 32; ++j) racc[j] = resb[cbase + j];
    #pragma unroll
    for (int j = 0; j < 64; ++j) sacc[j] = skipb[obase + j];
    for (int r = 0; r < C; ++r) {
        float gv = lds[r * TT + lane];
        const float* wr = resT + r * C + cbase;
        const float* wsk = skipT + r * S + obase;
        #pragma unroll
        for (int j = 0; j < 32; ++j) racc[j] = fmaf(wr[j], gv, racc[j]);
        #pragma unroll
        for (int j = 0; j < 64; ++j) sacc[j] = fmaf(wsk[j], gv, sacc[j]);
    }

    float* hout_n = h_out + (size_t)n * C * WLEN;
    #pragma unroll
    for (int j = 0; j < 32; ++j) {
        int c = cbase + j;
        hout_n[c * WLEN + t] = racc[j] + hin_n[c * WLEN + t];
    }
    float* sk = skips + (size_t)n * S * WLEN;
    #pragma unroll
    for (int j = 0; j < 64; ++j) {
        int o = obase + j;
        if (FIRST)
            sk[o * WLEN + t] = sacc[j];
        else
            sk[o * WLEN + t] += sacc[j];
    }
}

// ---------------- final head, in place on d_out ----------------
// out[n,:,t] = b_w @ relu(a_w @ relu(skips[n,:,t]) + a_b) + b_b
__global__ __launch_bounds__(256, 2) void final_kernel(
    float* __restrict__ out,
    const float* __restrict__ aT, const float* __restrict__ ab,
    const float* __restrict__ bT, const float* __restrict__ bb) {
    __shared__ float lds[S * TT];  // 64 KB
    const int n = blockIdx.y;
    const int t0 = blockIdx.x * TT;
    const int wave = __builtin_amdgcn_readfirstlane(threadIdx.x >> 6);
    const int lane = threadIdx.x & 63;
    const int t = t0 + lane;
    const int obase = wave * 64;
    float* on = out + (size_t)n * S * WLEN;

    // z = relu(skips) -> LDS
    #pragma unroll
    for (int j = 0; j < 64; ++j) {
        int flat = j * 256 + threadIdx.x;
        int s = flat >> 6, tt = flat & 63;
        float v = on[s * WLEN + t0 + tt];
        lds[flat] = v > 0.0f ? v : 0.0f;
    }
    __syncthreads();

    // z2 = relu(a_w @ z + a_b)
    float acc[64];
    #pragma unroll
    for (int j = 0; j < 64; ++j) acc[j] = ab[obase + j];
    for (int s = 0; s < S; ++s) {
        float zv = lds[s * TT + lane];
        const float* wa = aT + s * S + obase;
        #pragma unroll
        for (int j = 0; j < 64; ++j) acc[j] = fmaf(wa[j], zv, acc[j]);
    }
    __syncthreads();  // all reads of z done before overwrite
    #pragma unroll
    for (int j = 0; j < 64; ++j) {
        float v = acc[j];
        lds[(obase + j) * TT + lane] = v > 0.0f ? v : 0.0f;
    }
    __syncthreads();

    // logits = b_w @ z2 + b_b
    #pragma unroll
    for (int j = 0; j < 64; ++j) acc[j] = bb[obase + j];
    for (int e = 0; e < S; ++e) {
        float zv = lds[e * TT + lane];
        const float* wb = bT + e * S + obase;
        #pragma unroll
        for (int j = 0; j < 64; ++j) acc[j] = fmaf(wb[j], zv, acc[j]);
    }
    #pragma unroll
    for (int j = 0; j < 64; ++j) on[(obase + j) * WLEN + t] = acc[j];
}

extern "C" void kernel_launch(void* const* d_in, const int* in_sizes, int n_in,
                              void* d_out, int out_size, void* d_ws, size_t ws_size,
                              hipStream_t stream) {
    (void)in_sizes; (void)n_in; (void)out_size; (void)ws_size;
    const float* x       = (const float*)d_in[0];
    const float* w_shift = (const float*)d_in[1];
    const float* b_shift = (const float*)d_in[2];
    const float* conv_w  = (const float*)d_in[3];
    const float* conv_b  = (const float*)d_in[4];
    const float* res_w   = (const float*)d_in[5];
    const float* res_b   = (const float*)d_in[6];
    const float* skip_w  = (const float*)d_in[7];
    const float* skip_b  = (const float*)d_in[8];
    const float* a_w     = (const float*)d_in[9];
    const float* a_b     = (const float*)d_in[10];
    const float* b_w     = (const float*)d_in[11];
    const float* b_b     = (const float*)d_in[12];
    float* out = (float*)d_out;

    float* ws = (float*)d_ws;
    size_t off = 0;
    float* hA    = ws + off; off += (size_t)NB * C * WLEN;
    float* hB    = ws + off; off += (size_t)NB * C * WLEN;
    float* convT = ws + off; off += (size_t)NLAYERS * 2 * C * S;
    float* resT  = ws + off; off += (size_t)NLAYERS * C * C;
    float* skipT = ws + off; off += (size_t)NLAYERS * C * S;
    float* aT    = ws + off; off += 256 * 256;
    float* bT    = ws + off; off += 256 * 256;
    // total ~20.3M floats (~81.4 MB) of ws

    prep_kernel<<<512, 256, 0, stream>>>(conv_w, res_w, skip_w, a_w, b_w,
                                         convT, resT, skipT, aT, bT);
    front_kernel<<<dim3(WLEN / 256, NB), 256, 0, stream>>>(x, w_shift, b_shift, hA);

    float* hin = hA;
    float* hout = hB;
    for (int l = 0; l < NLAYERS; ++l) {
        int dil = 1 << (l % 10);
        if (l == 0) {
            layer_kernel<true><<<dim3(WLEN / TT, NB), 256, 0, stream>>>(
                hin, hout, out,
                convT + (size_t)l * 2 * C * S, conv_b + l * S,
                resT + (size_t)l * C * C, res_b + l * C,
                skipT + (size_t)l * C * S, skip_b + l * S, dil);
        } else {
            layer_kernel<false><<<dim3(WLEN / TT, NB), 256, 0, stream>>>(
                hin, hout, out,
                convT + (size_t)l * 2 * C * S, conv_b + l * S,
                resT + (size_t)l * C * C, res_b + l * C,
                skipT + (size_t)l * C * S, skip_b + l * S, dil);
        }
        float* tmp = hin; hin = hout; hout = tmp;
    }

    final_kernel<<<dim3(WLEN / TT, NB), 256, 0, stream>>>(out, aT, a_b, bT, b_b);
}

// Round 2
// 1887.050 us; speedup vs baseline: 8.6188x; 8.6188x over previous
//
#include <hip/hip_runtime.h>
#include <math.h>

// WaveNet forward, round 2: f16 MFMA (16x16x32, f32 accumulate).
// N=4, W=16384, C=128, S=256, 30 layers, kernel=2.
//
// Residual stream (h) and skip accumulation stay f32; only matmul operands
// are f16. Weights pre-packed into MFMA A-fragment-linear order by prep.
// LDS = 64 x 264 f16 = 33.8 KB -> 4 blocks/CU.
//
// MFMA 16x16x32 layouts (verified per guide m89/m120):
//   A: lane holds A[m=lane&15][k=(lane>>4)*8+j], j=0..7  (8 f16 = 4 VGPRs)
//   B: lane holds B[k=(lane>>4)*8+j][n=lane&15]
//   D: lane holds D[row=(lane>>4)*4+reg][col=lane&15]    (4 f32)

#define NB 4
#define WLEN 16384
#define C 128
#define S 256
#define NLAYERS 30
#define TT 64
#define ROW 264  // LDS row stride in f16 (256 + 8 pad; 528 B, 16B-aligned)

typedef _Float16 half8 __attribute__((ext_vector_type(8)));
typedef float floatx4 __attribute__((ext_vector_type(4)));

__device__ __forceinline__ float sigmoidf_(float v) {
    return 1.0f / (1.0f + __expf(-v));
}

// ---------------- weight packing ----------------
// Packs an MxK f32 matrix into MFMA A-fragment-linear f16 order:
//   dst[(((mt*(K/32)+ks)*64)+lane)*8 + j] = src[m= mt*16+(lane&15)][k= ks*32+(lane>>4)*8+j]
// Sizes (f16): convW 30*256*256, rsW 30*384*128, aW 256*256, bW 256*256.
__global__ void prep_kernel(const float* __restrict__ conv_w,
                            const float* __restrict__ res_w,
                            const float* __restrict__ skip_w,
                            const float* __restrict__ a_w,
                            const float* __restrict__ b_w,
                            _Float16* __restrict__ cw,
                            _Float16* __restrict__ rs,
                            _Float16* __restrict__ aw,
                            _Float16* __restrict__ bw) {
    const int ncw = NLAYERS * 256 * 256;
    const int nrs = NLAYERS * 384 * 128;
    const int nab = 256 * 256;
    const int total = ncw + nrs + nab + nab;
    for (int idx = blockIdx.x * blockDim.x + threadIdx.x; idx < total;
         idx += gridDim.x * blockDim.x) {
        int i = idx;
        if (i < ncw) {
            // per-layer M=256, K=256 (k = 2*in + tap)
            int j = i & 7, lane = (i >> 3) & 63, rest = i >> 9;
            int ks = rest & 7; rest >>= 3;          // K/32 = 8
            int mt = rest & 15; int l = rest >> 4;  // M/16 = 16
            int m = mt * 16 + (lane & 15);
            int k = ks * 32 + (lane >> 4) * 8 + j;
            int in = k >> 1, tap = k & 1;
            cw[i] = (_Float16)conv_w[(((size_t)l * 256 + m) * 128 + in) * 2 + tap];
        } else if (i < ncw + nrs) {
            i -= ncw;
            // per-layer M=384 (res 0..127, skip 128..383), K=128
            int j = i & 7, lane = (i >> 3) & 63, rest = i >> 9;
            int ks = rest & 3; rest >>= 2;          // K/32 = 4
            int mt = rest % 24; int l = rest / 24;  // M/16 = 24
            int m = mt * 16 + (lane & 15);
            int k = ks * 32 + (lane >> 4) * 8 + j;
            float v;
            if (m < 128) v = res_w[((size_t)l * 128 + m) * 128 + k];
            else         v = skip_w[((size_t)l * 256 + (m - 128)) * 128 + k];
            rs[idx - ncw] = (_Float16)v;
        } else if (i < ncw + nrs + nab) {
            i -= ncw + nrs;
            int j = i & 7, lane = (i >> 3) & 63, rest = i >> 9;
            int ks = rest & 7; int mt = rest >> 3;
            int m = mt * 16 + (lane & 15);
            int k = ks * 32 + (lane >> 4) * 8 + j;
            aw[i] = (_Float16)a_w[m * 256 + k];
        } else {
            i -= ncw + nrs + nab;
            int j = i & 7, lane = (i >> 3) & 63, rest = i >> 9;
            int ks = rest & 7; int mt = rest >> 3;
            int m = mt * 16 + (lane & 15);
            int k = ks * 32 + (lane >> 4) * 8 + j;
            bw[i] = (_Float16)b_w[m * 256 + k];
        }
    }
}

// ---------------- front (shifted causal conv, k=2, dil=1), f32 ----------------
__global__ void front_kernel(const float* __restrict__ x,
                             const float* __restrict__ w_shift,
                             const float* __restrict__ b_shift,
                             float* __restrict__ h) {
    const int n = blockIdx.y;
    const int t = blockIdx.x * 256 + threadIdx.x;
    float x1 = (t >= 1) ? x[n * WLEN + t - 1] : 0.0f;
    float x2 = (t >= 2) ? x[n * WLEN + t - 2] : 0.0f;
    #pragma unroll 4
    for (int c = 0; c < C; ++c) {
        float v = fmaf(w_shift[2 * c], x2, fmaf(w_shift[2 * c + 1], x1, b_shift[c]));
        h[(n * C + c) * WLEN + t] = v;
    }
}

// ---------------- one residual layer (MFMA) ----------------
template <bool FIRST>
__global__ __launch_bounds__(256, 4) void layer_kernel(
    const float* __restrict__ h_in, float* __restrict__ h_out,
    float* __restrict__ skips,
    const _Float16* __restrict__ cw, const float* __restrict__ cb,
    const _Float16* __restrict__ rsw, const float* __restrict__ rb,
    const float* __restrict__ sb, int d) {
    __shared__ _Float16 X[TT * ROW];  // 33792 B
    const int n = blockIdx.y;
    const int t0 = blockIdx.x * TT;
    const int tid = threadIdx.x;
    const int wave = __builtin_amdgcn_readfirstlane(tid >> 6);
    const int lane = tid & 63;
    const int q = lane >> 4;       // quad 0..3
    const int ml = lane & 15;

    const float* hn = h_in + (size_t)n * C * WLEN;

    // ---- stage Xcat f16 into LDS: X[t][k], k = 2*in + tap (tap0 = t-d, tap1 = t)
    {
        const int trow = 16 * wave + ml;       // this thread's t (one per thread)
        const int t = t0 + trow;
        #pragma unroll 4
        for (int it = 0; it < 32; ++it) {
            int i = 4 * it + q;                // input channel 0..127
            float v1 = hn[i * WLEN + t];
            int tb = t - d;
            float v0 = (tb >= 0) ? hn[i * WLEN + tb] : 0.0f;
            _Float16 p[2] = {(_Float16)v0, (_Float16)v1};
            *(uint32_t*)&X[trow * ROW + 2 * i] = *(uint32_t*)p;  // ds_write_b32
        }
    }
    __syncthreads();

    // ---- conv GEMM: D[256 o][64 t], K=256. Wave owns channels 64w..64w+63.
    floatx4 acc[4][4];
    #pragma unroll
    for (int mt = 0; mt < 4; ++mt) {
        #pragma unroll
        for (int r = 0; r < 4; ++r) {
            float bias = cb[64 * wave + mt * 16 + q * 4 + r];
            #pragma unroll
            for (int nt = 0; nt < 4; ++nt) acc[mt][nt][r] = bias;
        }
    }
    const _Float16* cwp = cw;
    for (int ks = 0; ks < 8; ++ks) {
        half8 b[4];
        #pragma unroll
        for (int nt = 0; nt < 4; ++nt)
            b[nt] = *(const half8*)&X[(nt * 16 + ml) * ROW + ks * 32 + q * 8];
        #pragma unroll
        for (int mt = 0; mt < 4; ++mt) {
            half8 a = *(const half8*)&cwp[((((4 * wave + mt) * 8) + ks) * 64 + lane) * 8];
            #pragma unroll
            for (int nt = 0; nt < 4; ++nt)
                acc[mt][nt] = __builtin_amdgcn_mfma_f32_16x16x32_f16(a, b[nt], acc[mt][nt], 0, 0, 0);
        }
    }
    __syncthreads();  // all B reads done before overwriting X with g

    // ---- write g (f16) to X[t][o], o = 0..255 (conflict-free pattern)
    #pragma unroll
    for (int mt = 0; mt < 4; ++mt)
        #pragma unroll
        for (int nt = 0; nt < 4; ++nt)
            #pragma unroll
            for (int r = 0; r < 4; ++r)
                X[(nt * 16 + ml) * ROW + 64 * wave + mt * 16 + q * 4 + r] =
                    (_Float16)acc[mt][nt][r];
    __syncthreads();

    // ---- GLU: gated[t][r] = g[t][r] * sigmoid(g[t][r+128]), in-place cols 0..127
    uint32_t ga[16], gb[16];
    #pragma unroll
    for (int it = 0; it < 16; ++it) {
        int idx = it * 256 + tid;
        int tr = idx >> 6, r2 = idx & 63;
        ga[it] = *(const uint32_t*)&X[tr * ROW + 2 * r2];
        gb[it] = *(const uint32_t*)&X[tr * ROW + 128 + 2 * r2];
    }
    __syncthreads();
    #pragma unroll
    for (int it = 0; it < 16; ++it) {
        int idx = it * 256 + tid;
        int tr = idx >> 6, r2 = idx & 63;
        _Float16 a0 = ((_Float16*)&ga[it])[0], a1 = ((_Float16*)&ga[it])[1];
        _Float16 b0 = ((_Float16*)&gb[it])[0], b1 = ((_Float16*)&gb[it])[1];
        _Float16 o2[2];
        o2[0] = (_Float16)((float)a0 * sigmoidf_((float)b0));
        o2[1] = (_Float16)((float)a1 * sigmoidf_((float)b1));
        *(uint32_t*)&X[tr * ROW + 2 * r2] = *(uint32_t*)o2;
    }
    __syncthreads();

    // ---- GEMM2a: skip (M rows 128..383 of rsW). Wave owns skip ch 64w..64w+63.
    {
        floatx4 sacc[4][4];
        #pragma unroll
        for (int mt = 0; mt < 4; ++mt) {
            #pragma unroll
            for (int r = 0; r < 4; ++r) {
                float bias = sb[64 * wave + mt * 16 + q * 4 + r];
                #pragma unroll
                for (int nt = 0; nt < 4; ++nt) sacc[mt][nt][r] = bias;
            }
        }
        for (int ks = 0; ks < 4; ++ks) {
            half8 b[4];
            #pragma unroll
            for (int nt = 0; nt < 4; ++nt)
                b[nt] = *(const half8*)&X[(nt * 16 + ml) * ROW + ks * 32 + q * 8];
            #pragma unroll
            for (int mt = 0; mt < 4; ++mt) {
                int mtile = 8 + 4 * wave + mt;
                half8 a = *(const half8*)&rsw[(((mtile * 4) + ks) * 64 + lane) * 8];
                #pragma unroll
                for (int nt = 0; nt < 4; ++nt)
                    sacc[mt][nt] = __builtin_amdgcn_mfma_f32_16x16x32_f16(a, b[nt], sacc[mt][nt], 0, 0, 0);
            }
        }
        float* sk = skips + (size_t)n * S * WLEN;
        #pragma unroll
        for (int mt = 0; mt < 4; ++mt)
            #pragma unroll
            for (int nt = 0; nt < 4; ++nt)
                #pragma unroll
                for (int r = 0; r < 4; ++r) {
                    int o = 64 * wave + mt * 16 + q * 4 + r;
                    int tt = t0 + nt * 16 + ml;
                    if (FIRST) sk[(size_t)o * WLEN + tt] = sacc[mt][nt][r];
                    else       sk[(size_t)o * WLEN + tt] += sacc[mt][nt][r];
                }
    }

    // ---- GEMM2b: res (M rows 0..127 of rsW). Wave owns res ch 32w..32w+31.
    {
        floatx4 racc[2][4];
        #pragma unroll
        for (int mt = 0; mt < 2; ++mt) {
            #pragma unroll
            for (int r = 0; r < 4; ++r) {
                float bias = rb[32 * wave + mt * 16 + q * 4 + r];
                #pragma unroll
                for (int nt = 0; nt < 4; ++nt) racc[mt][nt][r] = bias;
            }
        }
        for (int ks = 0; ks < 4; ++ks) {
            half8 b[4];
            #pragma unroll
            for (int nt = 0; nt < 4; ++nt)
                b[nt] = *(const half8*)&X[(nt * 16 + ml) * ROW + ks * 32 + q * 8];
            #pragma unroll
            for (int mt = 0; mt < 2; ++mt) {
                int mtile = 2 * wave + mt;
                half8 a = *(const half8*)&rsw[(((mtile * 4) + ks) * 64 + lane) * 8];
                #pragma unroll
                for (int nt = 0; nt < 4; ++nt)
                    racc[mt][nt] = __builtin_amdgcn_mfma_f32_16x16x32_f16(a, b[nt], racc[mt][nt], 0, 0, 0);
            }
        }
        float* ho = h_out + (size_t)n * C * WLEN;
        #pragma unroll
        for (int mt = 0; mt < 2; ++mt)
            #pragma unroll
            for (int nt = 0; nt < 4; ++nt)
                #pragma unroll
                for (int r = 0; r < 4; ++r) {
                    int c = 32 * wave + mt * 16 + q * 4 + r;
                    int tt = t0 + nt * 16 + ml;
                    ho[(size_t)c * WLEN + tt] = racc[mt][nt][r] + hn[(size_t)c * WLEN + tt];
                }
    }
}

// ---------------- final head (MFMA), in place on d_out ----------------
__global__ __launch_bounds__(256, 4) void final_kernel(
    float* __restrict__ out,
    const _Float16* __restrict__ aw, const float* __restrict__ ab,
    const _Float16* __restrict__ bw, const float* __restrict__ bb) {
    __shared__ _Float16 X[TT * ROW];
    const int n = blockIdx.y;
    const int t0 = blockIdx.x * TT;
    const int tid = threadIdx.x;
    const int wave = __builtin_amdgcn_readfirstlane(tid >> 6);
    const int lane = tid & 63;
    const int q = lane >> 4;
    const int ml = lane & 15;
    float* on = out + (size_t)n * S * WLEN;

    // ---- stage z = relu(skips) f16 -> X[t][s]
    {
        const int trow = 16 * wave + ml;
        const int t = t0 + trow;
        #pragma unroll 4
        for (int it = 0; it < 32; ++it) {
            int s0 = 8 * it + 2 * q;  // even s; thread covers (s0, s0+1)
            float v0 = on[s0 * WLEN + t];
            float v1 = on[(s0 + 1) * WLEN + t];
            _Float16 p[2] = {(_Float16)(v0 > 0.f ? v0 : 0.f),
                             (_Float16)(v1 > 0.f ? v1 : 0.f)};
            *(uint32_t*)&X[trow * ROW + s0] = *(uint32_t*)p;
        }
    }
    __syncthreads();

    // ---- GEMM1: z2 = relu(a_w @ z + a_b). Wave owns out ch 64w..64w+63.
    floatx4 acc[4][4];
    #pragma unroll
    for (int mt = 0; mt < 4; ++mt) {
        #pragma unroll
        for (int r = 0; r < 4; ++r) {
            float bias = ab[64 * wave + mt * 16 + q * 4 + r];
            #pragma unroll
            for (int nt = 0; nt < 4; ++nt) acc[mt][nt][r] = bias;
        }
    }
    for (int ks = 0; ks < 8; ++ks) {
        half8 b[4];
        #pragma unroll
        for (int nt = 0; nt < 4; ++nt)
            b[nt] = *(const half8*)&X[(nt * 16 + ml) * ROW + ks * 32 + q * 8];
        #pragma unroll
        for (int mt = 0; mt < 4; ++mt) {
            half8 a = *(const half8*)&aw[((((4 * wave + mt) * 8) + ks) * 64 + lane) * 8];
            #pragma unroll
            for (int nt = 0; nt < 4; ++nt)
                acc[mt][nt] = __builtin_amdgcn_mfma_f32_16x16x32_f16(a, b[nt], acc[mt][nt], 0, 0, 0);
        }
    }
    __syncthreads();
    #pragma unroll
    for (int mt = 0; mt < 4; ++mt)
        #pragma unroll
        for (int nt = 0; nt < 4; ++nt)
            #pragma unroll
            for (int r = 0; r < 4; ++r) {
                float v = acc[mt][nt][r];
                X[(nt * 16 + ml) * ROW + 64 * wave + mt * 16 + q * 4 + r] =
                    (_Float16)(v > 0.f ? v : 0.f);
            }
    __syncthreads();

    // ---- GEMM2: logits = b_w @ z2 + b_b, stored in place.
    #pragma unroll
    for (int mt = 0; mt < 4; ++mt) {
        #pragma unroll
        for (int r = 0; r < 4; ++r) {
            float bias = bb[64 * wave + mt * 16 + q * 4 + r];
            #pragma unroll
            for (int nt = 0; nt < 4; ++nt) acc[mt][nt][r] = bias;
        }
    }
    for (int ks = 0; ks < 8; ++ks) {
        half8 b[4];
        #pragma unroll
        for (int nt = 0; nt < 4; ++nt)
            b[nt] = *(const half8*)&X[(nt * 16 + ml) * ROW + ks * 32 + q * 8];
        #pragma unroll
        for (int mt = 0; mt < 4; ++mt) {
            half8 a = *(const half8*)&bw[((((4 * wave + mt) * 8) + ks) * 64 + lane) * 8];
            #pragma unroll
            for (int nt = 0; nt < 4; ++nt)
                acc[mt][nt] = __builtin_amdgcn_mfma_f32_16x16x32_f16(a, b[nt], acc[mt][nt], 0, 0, 0);
        }
    }
    #pragma unroll
    for (int mt = 0; mt < 4; ++mt)
        #pragma unroll
        for (int nt = 0; nt < 4; ++nt)
            #pragma unroll
            for (int r = 0; r < 4; ++r) {
                int o = 64 * wave + mt * 16 + q * 4 + r;
                int tt = t0 + nt * 16 + ml;
                on[(size_t)o * WLEN + tt] = acc[mt][nt][r];
            }
}

extern "C" void kernel_launch(void* const* d_in, const int* in_sizes, int n_in,
                              void* d_out, int out_size, void* d_ws, size_t ws_size,
                              hipStream_t stream) {
    (void)in_sizes; (void)n_in; (void)out_size; (void)ws_size;
    const float* x       = (const float*)d_in[0];
    const float* w_shift = (const float*)d_in[1];
    const float* b_shift = (const float*)d_in[2];
    const float* conv_w  = (const float*)d_in[3];
    const float* conv_b  = (const float*)d_in[4];
    const float* res_w   = (const float*)d_in[5];
    const float* res_b   = (const float*)d_in[6];
    const float* skip_w  = (const float*)d_in[7];
    const float* skip_b  = (const float*)d_in[8];
    const float* a_w     = (const float*)d_in[9];
    const float* a_b     = (const float*)d_in[10];
    const float* b_w     = (const float*)d_in[11];
    const float* b_b     = (const float*)d_in[12];
    float* out = (float*)d_out;

    char* ws = (char*)d_ws;
    size_t off = 0;
    float* hA = (float*)(ws + off); off += (size_t)NB * C * WLEN * 4;
    float* hB = (float*)(ws + off); off += (size_t)NB * C * WLEN * 4;
    _Float16* cw = (_Float16*)(ws + off); off += (size_t)NLAYERS * 256 * 256 * 2;
    _Float16* rs = (_Float16*)(ws + off); off += (size_t)NLAYERS * 384 * 128 * 2;
    _Float16* aw = (_Float16*)(ws + off); off += 256 * 256 * 2;
    _Float16* bw = (_Float16*)(ws + off); off += 256 * 256 * 2;
    // total ~74.3 MB

    prep_kernel<<<512, 256, 0, stream>>>(conv_w, res_w, skip_w, a_w, b_w,
                                         cw, rs, aw, bw);
    front_kernel<<<dim3(WLEN / 256, NB), 256, 0, stream>>>(x, w_shift, b_shift, hA);

    float* hin = hA;
    float* hout = hB;
    for (int l = 0; l < NLAYERS; ++l) {
        int dil = 1 << (l % 10);
        const _Float16* cwp = cw + (size_t)l * 256 * 256;
        const _Float16* rsp = rs + (size_t)l * 384 * 128;
        if (l == 0) {
            layer_kernel<true><<<dim3(WLEN / TT, NB), 256, 0, stream>>>(
                hin, hout, out, cwp, conv_b + l * 256,
                rsp, res_b + l * 128, skip_b + l * 256, dil);
        } else {
            layer_kernel<false><<<dim3(WLEN / TT, NB), 256, 0, stream>>>(
                hin, hout, out, cwp, conv_b + l * 256,
                rsp, res_b + l * 128, skip_b + l * 256, dil);
        }
        float* tmp = hin; hin = hout; hout = tmp;
    }

    final_kernel<<<dim3(WLEN / TT, NB), 256, 0, stream>>>(out, aw, a_b, bw, b_b);
}

// Round 3
// 1791.551 us; speedup vs baseline: 9.0782x; 1.0533x over previous
//
#include <hip/hip_runtime.h>
#include <math.h>

// WaveNet forward, round 3: eliminate per-layer skip RMW.
// Each layer writes gated (f16, fragment-linear) to ws; skip GEMM + f32
// register accumulation is fused into the final head (or grouped skip_accum
// kernels if ws is too small for all 30 gated buffers).
// GLU computed in registers via interleaved conv weight rows (a0,b0,a1,b1,...).

#define NB 4
#define WLEN 16384
#define C 128
#define S 256
#define NLAYERS 30
#define TT 64
#define NTB (WLEN / TT)  // 256 t-tiles per sample
#define ROW 264          // LDS row stride in f16
#define GSLOT ((size_t)NB * NTB * 8192)  // f16 elems per gated layer slot (16.78 MB)

typedef _Float16 half8 __attribute__((ext_vector_type(8)));
typedef float floatx4 __attribute__((ext_vector_type(4)));

__device__ __forceinline__ float sigmoidf_(float v) {
    return 1.0f / (1.0f + __expf(-v));
}

// ---------------- weight packing ----------------
// cw : conv, per layer M=256 rows INTERLEAVED (m'=2r+s; s=0 -> a-row r, s=1 -> b-row r+128),
//      K=256 (k=2*in+tap), frag-linear [mt][ks][lane][8]
// rsw: res,  per layer M=128, K=128, frag-linear [mt][ks][lane][8]
// skw: skip, per layer M=256, K=128, frag-linear [mt][ks][lane][8]
// aw/bw: head, M=256, K=256
// cbp: conv bias in interleaved row order; ssum: sum over layers of skip_b
__global__ void prep_kernel(const float* __restrict__ conv_w,
                            const float* __restrict__ res_w,
                            const float* __restrict__ skip_w,
                            const float* __restrict__ a_w,
                            const float* __restrict__ b_w,
                            const float* __restrict__ conv_b,
                            const float* __restrict__ skip_b,
                            _Float16* __restrict__ cw,
                            _Float16* __restrict__ rsw,
                            _Float16* __restrict__ skw,
                            _Float16* __restrict__ aw,
                            _Float16* __restrict__ bw,
                            float* __restrict__ cbp,
                            float* __restrict__ ssum) {
    const int ncw = NLAYERS * 256 * 256;
    const int nrs = NLAYERS * 128 * 128;
    const int nsk = NLAYERS * 256 * 128;
    const int nab = 256 * 256;
    const int ncb = NLAYERS * 256;
    const int total = ncw + nrs + nsk + nab + nab + ncb + 256;
    for (int idx = blockIdx.x * blockDim.x + threadIdx.x; idx < total;
         idx += gridDim.x * blockDim.x) {
        int i = idx;
        if (i < ncw) {
            int j = i & 7, lane = (i >> 3) & 63, rest = i >> 9;
            int ks = rest & 7; rest >>= 3;
            int mt = rest & 15; int l = rest >> 4;
            int mp = mt * 16 + (lane & 15);
            int orow = (mp >> 1) + (mp & 1) * 128;  // interleave
            int k = ks * 32 + (lane >> 4) * 8 + j;
            cw[i] = (_Float16)conv_w[(((size_t)l * 256 + orow) * 128 + (k >> 1)) * 2 + (k & 1)];
        } else if (i < ncw + nrs) {
            i -= ncw;
            int j = i & 7, lane = (i >> 3) & 63, rest = i >> 9;
            int ks = rest & 3; rest >>= 2;
            int mt = rest & 7; int l = rest >> 3;
            int m = mt * 16 + (lane & 15);
            int k = ks * 32 + (lane >> 4) * 8 + j;
            rsw[i] = (_Float16)res_w[((size_t)l * 128 + m) * 128 + k];
        } else if (i < ncw + nrs + nsk) {
            i -= ncw + nrs;
            int j = i & 7, lane = (i >> 3) & 63, rest = i >> 9;
            int ks = rest & 3; rest >>= 2;
            int mt = rest & 15; int l = rest >> 4;
            int m = mt * 16 + (lane & 15);
            int k = ks * 32 + (lane >> 4) * 8 + j;
            skw[i] = (_Float16)skip_w[((size_t)l * 256 + m) * 128 + k];
        } else if (i < ncw + nrs + nsk + nab) {
            i -= ncw + nrs + nsk;
            int j = i & 7, lane = (i >> 3) & 63, rest = i >> 9;
            int ks = rest & 7; int mt = rest >> 3;
            aw[i] = (_Float16)a_w[(mt * 16 + (lane & 15)) * 256 + ks * 32 + (lane >> 4) * 8 + j];
        } else if (i < ncw + nrs + nsk + 2 * nab) {
            i -= ncw + nrs + nsk + nab;
            int j = i & 7, lane = (i >> 3) & 63, rest = i >> 9;
            int ks = rest & 7; int mt = rest >> 3;
            bw[i] = (_Float16)b_w[(mt * 16 + (lane & 15)) * 256 + ks * 32 + (lane >> 4) * 8 + j];
        } else if (i < ncw + nrs + nsk + 2 * nab + ncb) {
            i -= ncw + nrs + nsk + 2 * nab;
            int mp = i & 255; int l = i >> 8;
            cbp[i] = conv_b[l * 256 + (mp >> 1) + (mp & 1) * 128];
        } else {
            i -= ncw + nrs + nsk + 2 * nab + ncb;
            float s = 0.f;
            for (int l = 0; l < NLAYERS; ++l) s += skip_b[l * 256 + i];
            ssum[i] = s;
        }
    }
}

// ---------------- front (shifted causal conv, k=2, dil=1), f32 ----------------
__global__ void front_kernel(const float* __restrict__ x,
                             const float* __restrict__ w_shift,
                             const float* __restrict__ b_shift,
                             float* __restrict__ h) {
    const int n = blockIdx.y;
    const int t = blockIdx.x * 256 + threadIdx.x;
    float x1 = (t >= 1) ? x[n * WLEN + t - 1] : 0.0f;
    float x2 = (t >= 2) ? x[n * WLEN + t - 2] : 0.0f;
    #pragma unroll 4
    for (int c = 0; c < C; ++c) {
        float v = fmaf(w_shift[2 * c], x2, fmaf(w_shift[2 * c + 1], x1, b_shift[c]));
        h[(n * C + c) * WLEN + t] = v;
    }
}

// ---------------- one residual layer ----------------
__global__ __launch_bounds__(256, 4) void layer_kernel(
    const float* __restrict__ h_in, float* __restrict__ h_out,
    _Float16* __restrict__ gout,
    const _Float16* __restrict__ cw, const float* __restrict__ cb,
    const _Float16* __restrict__ rsw, const float* __restrict__ rb, int d) {
    __shared__ _Float16 X[TT * ROW];  // 33792 B
    const int n = blockIdx.y, tb = blockIdx.x, t0 = tb * TT;
    const int tid = threadIdx.x;
    const int wave = __builtin_amdgcn_readfirstlane(tid >> 6);
    const int lane = tid & 63, q = lane >> 4, ml = lane & 15;
    const float* hn = h_in + (size_t)n * C * WLEN;

    // ---- stage h f16 into X[t][k], k = 2*in + tap (tap0 = t-d, tap1 = t)
    {
        const int trow = 16 * wave + ml;
        const int t = t0 + trow, tbk = t - d;
        #pragma unroll 4
        for (int it = 0; it < 32; ++it) {
            int i = 4 * it + q;
            float v1 = hn[i * WLEN + t];
            float v0 = (tbk >= 0) ? hn[i * WLEN + tbk] : 0.0f;
            _Float16 p[2] = {(_Float16)v0, (_Float16)v1};
            *(uint32_t*)&X[trow * ROW + 2 * i] = *(uint32_t*)p;
        }
    }
    __syncthreads();

    // ---- conv GEMM (interleaved rows): D[m'=64w+16mt+4q+reg][t=16nt+ml]
    floatx4 acc[4][4];
    #pragma unroll
    for (int mt = 0; mt < 4; ++mt)
        #pragma unroll
        for (int r = 0; r < 4; ++r) {
            float bias = cb[64 * wave + mt * 16 + q * 4 + r];
            #pragma unroll
            for (int nt = 0; nt < 4; ++nt) acc[mt][nt][r] = bias;
        }
    for (int ks = 0; ks < 8; ++ks) {
        half8 b[4];
        #pragma unroll
        for (int nt = 0; nt < 4; ++nt)
            b[nt] = *(const half8*)&X[(nt * 16 + ml) * ROW + ks * 32 + q * 8];
        #pragma unroll
        for (int mt = 0; mt < 4; ++mt) {
            half8 a = *(const half8*)&cw[((((4 * wave + mt) * 8) + ks) * 64 + lane) * 8];
            #pragma unroll
            for (int nt = 0; nt < 4; ++nt)
                acc[mt][nt] = __builtin_amdgcn_mfma_f32_16x16x32_f16(a, b[nt], acc[mt][nt], 0, 0, 0);
        }
    }
    __syncthreads();  // all conv B reads done

    // ---- GLU in registers: rows 4q+{0,1}=a/b for r=32w+8mt+2q, 4q+{2,3} for r+1
    #pragma unroll
    for (int mt = 0; mt < 4; ++mt)
        #pragma unroll
        for (int nt = 0; nt < 4; ++nt) {
            float g0 = acc[mt][nt][0] * sigmoidf_(acc[mt][nt][1]);
            float g1 = acc[mt][nt][2] * sigmoidf_(acc[mt][nt][3]);
            _Float16 p[2] = {(_Float16)g0, (_Float16)g1};
            *(uint32_t*)&X[(nt * 16 + ml) * ROW + 32 * wave + mt * 8 + 2 * q] = *(uint32_t*)p;
        }
    __syncthreads();

    // ---- gated -> global, fragment-linear (wave w stores frags nt=w, ks=0..3)
    {
        _Float16* gb = gout + (size_t)(n * NTB + tb) * 8192;
        #pragma unroll
        for (int ks = 0; ks < 4; ++ks) {
            half8 v = *(const half8*)&X[(wave * 16 + ml) * ROW + ks * 32 + q * 8];
            *(half8*)&gb[((wave * 4 + ks) * 64 + lane) * 8] = v;
        }
    }

    // ---- res GEMM: M=128, wave owns mtiles {2w,2w+1}
    floatx4 racc[2][4];
    #pragma unroll
    for (int mt = 0; mt < 2; ++mt)
        #pragma unroll
        for (int r = 0; r < 4; ++r) {
            float bias = rb[32 * wave + mt * 16 + q * 4 + r];
            #pragma unroll
            for (int nt = 0; nt < 4; ++nt) racc[mt][nt][r] = bias;
        }
    #pragma unroll
    for (int ks = 0; ks < 4; ++ks) {
        half8 b[4];
        #pragma unroll
        for (int nt = 0; nt < 4; ++nt)
            b[nt] = *(const half8*)&X[(nt * 16 + ml) * ROW + ks * 32 + q * 8];
        #pragma unroll
        for (int mt = 0; mt < 2; ++mt) {
            half8 a = *(const half8*)&rsw[((((2 * wave + mt) * 4) + ks) * 64 + lane) * 8];
            #pragma unroll
            for (int nt = 0; nt < 4; ++nt)
                racc[mt][nt] = __builtin_amdgcn_mfma_f32_16x16x32_f16(a, b[nt], racc[mt][nt], 0, 0, 0);
        }
    }
    float* ho = h_out + (size_t)n * C * WLEN;
    #pragma unroll
    for (int mt = 0; mt < 2; ++mt)
        #pragma unroll
        for (int nt = 0; nt < 4; ++nt)
            #pragma unroll
            for (int r = 0; r < 4; ++r) {
                int c = 32 * wave + mt * 16 + q * 4 + r;
                int tt = t0 + nt * 16 + ml;
                ho[(size_t)c * WLEN + tt] = racc[mt][nt][r] + hn[(size_t)c * WLEN + tt];
            }
}

// ---------------- shared skip-GEMM step ----------------
__device__ __forceinline__ void skip_gemm(floatx4 (&acc)[4][4],
                                          const _Float16* __restrict__ gbase,
                                          const _Float16* __restrict__ skwL,
                                          int wave, int lane) {
    #pragma unroll
    for (int ks = 0; ks < 4; ++ks) {
        half8 b[4];
        #pragma unroll
        for (int nt = 0; nt < 4; ++nt)
            b[nt] = *(const half8*)&gbase[((nt * 4 + ks) * 64 + lane) * 8];
        #pragma unroll
        for (int mt = 0; mt < 4; ++mt) {
            half8 a = *(const half8*)&skwL[((((4 * wave + mt) * 4) + ks) * 64 + lane) * 8];
            #pragma unroll
            for (int nt = 0; nt < 4; ++nt)
                acc[mt][nt] = __builtin_amdgcn_mfma_f32_16x16x32_f16(a, b[nt], acc[mt][nt], 0, 0, 0);
        }
    }
}

// ---------------- fused skip-sum + head (all 30 gated buffers present) ----------------
__global__ __launch_bounds__(256, 4) void final_all_kernel(
    float* __restrict__ out, const _Float16* __restrict__ gated,
    const _Float16* __restrict__ skw, const float* __restrict__ ssum,
    const _Float16* __restrict__ aw, const float* __restrict__ ab,
    const _Float16* __restrict__ bw, const float* __restrict__ bb) {
    __shared__ _Float16 X[TT * ROW];
    const int n = blockIdx.y, tb = blockIdx.x, t0 = tb * TT;
    const int tid = threadIdx.x;
    const int wave = __builtin_amdgcn_readfirstlane(tid >> 6);
    const int lane = tid & 63, q = lane >> 4, ml = lane & 15;

    floatx4 acc[4][4];
    #pragma unroll
    for (int mt = 0; mt < 4; ++mt)
        #pragma unroll
        for (int r = 0; r < 4; ++r) {
            float bias = ssum[64 * wave + mt * 16 + q * 4 + r];
            #pragma unroll
            for (int nt = 0; nt < 4; ++nt) acc[mt][nt][r] = bias;
        }
    const size_t tile = (size_t)(n * NTB + tb) * 8192;
    for (int l = 0; l < NLAYERS; ++l)
        skip_gemm(acc, gated + (size_t)l * GSLOT + tile, skw + (size_t)l * 32768, wave, lane);

    // z = relu(skips) -> X[t][s]
    #pragma unroll
    for (int mt = 0; mt < 4; ++mt)
        #pragma unroll
        for (int nt = 0; nt < 4; ++nt)
            #pragma unroll
            for (int r = 0; r < 4; ++r) {
                float v = acc[mt][nt][r];
                X[(nt * 16 + ml) * ROW + 64 * wave + mt * 16 + q * 4 + r] =
                    (_Float16)(v > 0.f ? v : 0.f);
            }
    __syncthreads();

    // z2 = relu(a_w @ z + a_b)
    #pragma unroll
    for (int mt = 0; mt < 4; ++mt)
        #pragma unroll
        for (int r = 0; r < 4; ++r) {
            float bias = ab[64 * wave + mt * 16 + q * 4 + r];
            #pragma unroll
            for (int nt = 0; nt < 4; ++nt) acc[mt][nt][r] = bias;
        }
    for (int ks = 0; ks < 8; ++ks) {
        half8 b[4];
        #pragma unroll
        for (int nt = 0; nt < 4; ++nt)
            b[nt] = *(const half8*)&X[(nt * 16 + ml) * ROW + ks * 32 + q * 8];
        #pragma unroll
        for (int mt = 0; mt < 4; ++mt) {
            half8 a = *(const half8*)&aw[((((4 * wave + mt) * 8) + ks) * 64 + lane) * 8];
            #pragma unroll
            for (int nt = 0; nt < 4; ++nt)
                acc[mt][nt] = __builtin_amdgcn_mfma_f32_16x16x32_f16(a, b[nt], acc[mt][nt], 0, 0, 0);
        }
    }
    __syncthreads();
    #pragma unroll
    for (int mt = 0; mt < 4; ++mt)
        #pragma unroll
        for (int nt = 0; nt < 4; ++nt)
            #pragma unroll
            for (int r = 0; r < 4; ++r) {
                float v = acc[mt][nt][r];
                X[(nt * 16 + ml) * ROW + 64 * wave + mt * 16 + q * 4 + r] =
                    (_Float16)(v > 0.f ? v : 0.f);
            }
    __syncthreads();

    // logits = b_w @ z2 + b_b
    #pragma unroll
    for (int mt = 0; mt < 4; ++mt)
        #pragma unroll
        for (int r = 0; r < 4; ++r) {
            float bias = bb[64 * wave + mt * 16 + q * 4 + r];
            #pragma unroll
            for (int nt = 0; nt < 4; ++nt) acc[mt][nt][r] = bias;
        }
    for (int ks = 0; ks < 8; ++ks) {
        half8 b[4];
        #pragma unroll
        for (int nt = 0; nt < 4; ++nt)
            b[nt] = *(const half8*)&X[(nt * 16 + ml) * ROW + ks * 32 + q * 8];
        #pragma unroll
        for (int mt = 0; mt < 4; ++mt) {
            half8 a = *(const half8*)&bw[((((4 * wave + mt) * 8) + ks) * 64 + lane) * 8];
            #pragma unroll
            for (int nt = 0; nt < 4; ++nt)
                acc[mt][nt] = __builtin_amdgcn_mfma_f32_16x16x32_f16(a, b[nt], acc[mt][nt], 0, 0, 0);
        }
    }
    float* on = out + (size_t)n * S * WLEN;
    #pragma unroll
    for (int mt = 0; mt < 4; ++mt)
        #pragma unroll
        for (int nt = 0; nt < 4; ++nt)
            #pragma unroll
            for (int r = 0; r < 4; ++r) {
                int o = 64 * wave + mt * 16 + q * 4 + r;
                int tt = t0 + nt * 16 + ml;
                on[(size_t)o * WLEN + tt] = acc[mt][nt][r];
            }
}

// ---------------- grouped skip accumulation (fallback, ws too small) ----------------
__global__ __launch_bounds__(256, 4) void skip_accum_kernel(
    float* __restrict__ skips, const _Float16* __restrict__ gated,
    const _Float16* __restrict__ skw, const float* __restrict__ ssum,
    int l0, int cnt, int first) {
    const int n = blockIdx.y, tb = blockIdx.x, t0 = tb * TT;
    const int tid = threadIdx.x;
    const int wave = __builtin_amdgcn_readfirstlane(tid >> 6);
    const int lane = tid & 63, q = lane >> 4, ml = lane & 15;

    floatx4 acc[4][4];
    #pragma unroll
    for (int mt = 0; mt < 4; ++mt)
        #pragma unroll
        for (int r = 0; r < 4; ++r) {
            float bias = first ? ssum[64 * wave + mt * 16 + q * 4 + r] : 0.0f;
            #pragma unroll
            for (int nt = 0; nt < 4; ++nt) acc[mt][nt][r] = bias;
        }
    const size_t tile = (size_t)(n * NTB + tb) * 8192;
    for (int g = 0; g < cnt; ++g)
        skip_gemm(acc, gated + (size_t)g * GSLOT + tile,
                  skw + (size_t)(l0 + g) * 32768, wave, lane);

    float* sk = skips + (size_t)n * S * WLEN;
    #pragma unroll
    for (int mt = 0; mt < 4; ++mt)
        #pragma unroll
        for (int nt = 0; nt < 4; ++nt)
            #pragma unroll
            for (int r = 0; r < 4; ++r) {
                int o = 64 * wave + mt * 16 + q * 4 + r;
                int tt = t0 + nt * 16 + ml;
                if (first) sk[(size_t)o * WLEN + tt] = acc[mt][nt][r];
                else       sk[(size_t)o * WLEN + tt] += acc[mt][nt][r];
            }
}

// ---------------- head only (fallback path), in place on d_out ----------------
__global__ __launch_bounds__(256, 4) void final_head_kernel(
    float* __restrict__ out,
    const _Float16* __restrict__ aw, const float* __restrict__ ab,
    const _Float16* __restrict__ bw, const float* __restrict__ bb) {
    __shared__ _Float16 X[TT * ROW];
    const int n = blockIdx.y, t0 = blockIdx.x * TT;
    const int tid = threadIdx.x;
    const int wave = __builtin_amdgcn_readfirstlane(tid >> 6);
    const int lane = tid & 63, q = lane >> 4, ml = lane & 15;
    float* on = out + (size_t)n * S * WLEN;

    {
        const int trow = 16 * wave + ml;
        const int t = t0 + trow;
        #pragma unroll 4
        for (int it = 0; it < 32; ++it) {
            int s0 = 8 * it + 2 * q;
            float v0 = on[s0 * WLEN + t];
            float v1 = on[(s0 + 1) * WLEN + t];
            _Float16 p[2] = {(_Float16)(v0 > 0.f ? v0 : 0.f),
                             (_Float16)(v1 > 0.f ? v1 : 0.f)};
            *(uint32_t*)&X[trow * ROW + s0] = *(uint32_t*)p;
        }
    }
    __syncthreads();

    floatx4 acc[4][4];
    #pragma unroll
    for (int mt = 0; mt < 4; ++mt)
        #pragma unroll
        for (int r = 0; r < 4; ++r) {
            float bias = ab[64 * wave + mt * 16 + q * 4 + r];
            #pragma unroll
            for (int nt = 0; nt < 4; ++nt) acc[mt][nt][r] = bias;
        }
    for (int ks = 0; ks < 8; ++ks) {
        half8 b[4];
        #pragma unroll
        for (int nt = 0; nt < 4; ++nt)
            b[nt] = *(const half8*)&X[(nt * 16 + ml) * ROW + ks * 32 + q * 8];
        #pragma unroll
        for (int mt = 0; mt < 4; ++mt) {
            half8 a = *(const half8*)&aw[((((4 * wave + mt) * 8) + ks) * 64 + lane) * 8];
            #pragma unroll
            for (int nt = 0; nt < 4; ++nt)
                acc[mt][nt] = __builtin_amdgcn_mfma_f32_16x16x32_f16(a, b[nt], acc[mt][nt], 0, 0, 0);
        }
    }
    __syncthreads();
    #pragma unroll
    for (int mt = 0; mt < 4; ++mt)
        #pragma unroll
        for (int nt = 0; nt < 4; ++nt)
            #pragma unroll
            for (int r = 0; r < 4; ++r) {
                float v = acc[mt][nt][r];
                X[(nt * 16 + ml) * ROW + 64 * wave + mt * 16 + q * 4 + r] =
                    (_Float16)(v > 0.f ? v : 0.f);
            }
    __syncthreads();

    #pragma unroll
    for (int mt = 0; mt < 4; ++mt)
        #pragma unroll
        for (int r = 0; r < 4; ++r) {
            float bias = bb[64 * wave + mt * 16 + q * 4 + r];
            #pragma unroll
            for (int nt = 0; nt < 4; ++nt) acc[mt][nt][r] = bias;
        }
    for (int ks = 0; ks < 8; ++ks) {
        half8 b[4];
        #pragma unroll
        for (int nt = 0; nt < 4; ++nt)
            b[nt] = *(const half8*)&X[(nt * 16 + ml) * ROW + ks * 32 + q * 8];
        #pragma unroll
        for (int mt = 0; mt < 4; ++mt) {
            half8 a = *(const half8*)&bw[((((4 * wave + mt) * 8) + ks) * 64 + lane) * 8];
            #pragma unroll
            for (int nt = 0; nt < 4; ++nt)
                acc[mt][nt] = __builtin_amdgcn_mfma_f32_16x16x32_f16(a, b[nt], acc[mt][nt], 0, 0, 0);
        }
    }
    #pragma unroll
    for (int mt = 0; mt < 4; ++mt)
        #pragma unroll
        for (int nt = 0; nt < 4; ++nt)
            #pragma unroll
            for (int r = 0; r < 4; ++r) {
                int o = 64 * wave + mt * 16 + q * 4 + r;
                int tt = t0 + nt * 16 + ml;
                on[(size_t)o * WLEN + tt] = acc[mt][nt][r];
            }
}

extern "C" void kernel_launch(void* const* d_in, const int* in_sizes, int n_in,
                              void* d_out, int out_size, void* d_ws, size_t ws_size,
                              hipStream_t stream) {
    (void)in_sizes; (void)n_in; (void)out_size;
    const float* x       = (const float*)d_in[0];
    const float* w_shift = (const float*)d_in[1];
    const float* b_shift = (const float*)d_in[2];
    const float* conv_w  = (const float*)d_in[3];
    const float* conv_b  = (const float*)d_in[4];
    const float* res_w   = (const float*)d_in[5];
    const float* res_b   = (const float*)d_in[6];
    const float* skip_w  = (const float*)d_in[7];
    const float* skip_b  = (const float*)d_in[8];
    const float* a_w     = (const float*)d_in[9];
    const float* a_b     = (const float*)d_in[10];
    const float* b_w     = (const float*)d_in[11];
    const float* b_b     = (const float*)d_in[12];
    float* out = (float*)d_out;

    char* ws = (char*)d_ws;
    size_t off = 0;
    float* hA = (float*)(ws + off); off += (size_t)NB * C * WLEN * 4;
    float* hB = (float*)(ws + off); off += (size_t)NB * C * WLEN * 4;
    _Float16* cw  = (_Float16*)(ws + off); off += (size_t)NLAYERS * 256 * 256 * 2;
    _Float16* rsw = (_Float16*)(ws + off); off += (size_t)NLAYERS * 128 * 128 * 2;
    _Float16* skw = (_Float16*)(ws + off); off += (size_t)NLAYERS * 256 * 128 * 2;
    _Float16* aw  = (_Float16*)(ws + off); off += 256 * 256 * 2;
    _Float16* bw  = (_Float16*)(ws + off); off += 256 * 256 * 2;
    float* cbp  = (float*)(ws + off); off += (size_t)NLAYERS * 256 * 4;
    float* ssum = (float*)(ws + off); off += 256 * 4;
    _Float16* gated = (_Float16*)(ws + off);

    long long avail = (long long)ws_size - (long long)off;
    int NG = (int)(avail / (long long)(GSLOT * 2));
    if (NG < 1) NG = 1;
    if (NG > NLAYERS) NG = NLAYERS;

    prep_kernel<<<512, 256, 0, stream>>>(conv_w, res_w, skip_w, a_w, b_w,
                                         conv_b, skip_b,
                                         cw, rsw, skw, aw, bw, cbp, ssum);
    front_kernel<<<dim3(WLEN / 256, NB), 256, 0, stream>>>(x, w_shift, b_shift, hA);

    const dim3 grid(NTB, NB);
    float* hin = hA;
    float* hout = hB;

    if (NG >= NLAYERS) {
        for (int l = 0; l < NLAYERS; ++l) {
            int dil = 1 << (l % 10);
            layer_kernel<<<grid, 256, 0, stream>>>(
                hin, hout, gated + (size_t)l * GSLOT,
                cw + (size_t)l * 65536, cbp + l * 256,
                rsw + (size_t)l * 16384, res_b + l * 128, dil);
            float* tmp = hin; hin = hout; hout = tmp;
        }
        final_all_kernel<<<grid, 256, 0, stream>>>(out, gated, skw, ssum,
                                                   aw, a_b, bw, b_b);
    } else {
        int l = 0, first = 1;
        while (l < NLAYERS) {
            int cnt = (NLAYERS - l < NG) ? (NLAYERS - l) : NG;
            for (int g = 0; g < cnt; ++g) {
                int ll = l + g;
                int dil = 1 << (ll % 10);
                layer_kernel<<<grid, 256, 0, stream>>>(
                    hin, hout, gated + (size_t)g * GSLOT,
                    cw + (size_t)ll * 65536, cbp + ll * 256,
                    rsw + (size_t)ll * 16384, res_b + ll * 128, dil);
                float* tmp = hin; hin = hout; hout = tmp;
            }
            skip_accum_kernel<<<grid, 256, 0, stream>>>(out, gated, skw, ssum,
                                                        l, cnt, first);
            first = 0;
            l += cnt;
        }
        final_head_kernel<<<grid, 256, 0, stream>>>(out, aw, a_b, bw, b_b);
    }
}

// Round 4
// 1678.341 us; speedup vs baseline: 9.6906x; 1.0675x over previous
//
#include <hip/hip_runtime.h>
#include <math.h>

// WaveNet forward, round 4: minimal-traffic layout.
// - h ping-pong in f16, layout [n][t][c] (t-major, channel-contiguous rows):
//   staging of both conv taps = contiguous b128 row copies.
// - skip accumulation fused into layer kernel, into a f16 FRAGMENT-LINEAR
//   chunk in ws: RMW is perfectly coalesced dwordx2 per lane. No gated
//   buffer, no skip_accum kernels, no ws-size-dependent paths.
// - head kernel: chunk -> relu -> a_w -> relu -> b_w -> logits (f32, d_out).
//
// MFMA 16x16x32_f16: A lane: A[m=lane&15][k=(lane>>4)*8+j]; D lane:
// D[row=(lane>>4)*4+reg][col=lane&15]. Conv A-rows interleaved (a0,b0,a1,b1..)
// so GLU happens in registers. Conv K order: k = tap*128 + c.

#define NB 4
#define WLEN 16384
#define C 128
#define S 256
#define NLAYERS 30
#define TT 64
#define NTB (WLEN / TT)   // 256 tiles per sample
#define XROW 264          // X row stride (f16): 256 + 8 pad
#define GROW 136          // G row stride (f16): 128 + 8 pad

typedef _Float16 half8 __attribute__((ext_vector_type(8)));
typedef _Float16 half4 __attribute__((ext_vector_type(4)));
typedef float floatx4 __attribute__((ext_vector_type(4)));

__device__ __forceinline__ float sigmoidf_(float v) {
    return 1.0f / (1.0f + __expf(-v));
}

// ---------------- weight packing ----------------
// cw : conv, per layer M=256 rows interleaved (m'=2r+s: s=0 a-row r, s=1 b-row r+128),
//      K=256 with k = tap*128 + c. Frag-linear [mt][ks][lane][8].
// rsw: res  M=128 K=128; skw: skip M=256 K=128; aw/bw: 256x256.
// cbp: conv bias interleaved; ssum: sum over layers of skip_b.
__global__ void prep_kernel(const float* __restrict__ conv_w,
                            const float* __restrict__ res_w,
                            const float* __restrict__ skip_w,
                            const float* __restrict__ a_w,
                            const float* __restrict__ b_w,
                            const float* __restrict__ conv_b,
                            const float* __restrict__ skip_b,
                            _Float16* __restrict__ cw,
                            _Float16* __restrict__ rsw,
                            _Float16* __restrict__ skw,
                            _Float16* __restrict__ aw,
                            _Float16* __restrict__ bw,
                            float* __restrict__ cbp,
                            float* __restrict__ ssum) {
    const int ncw = NLAYERS * 256 * 256;
    const int nrs = NLAYERS * 128 * 128;
    const int nsk = NLAYERS * 256 * 128;
    const int nab = 256 * 256;
    const int ncb = NLAYERS * 256;
    const int total = ncw + nrs + nsk + nab + nab + ncb + 256;
    for (int idx = blockIdx.x * blockDim.x + threadIdx.x; idx < total;
         idx += gridDim.x * blockDim.x) {
        int i = idx;
        if (i < ncw) {
            int j = i & 7, lane = (i >> 3) & 63, rest = i >> 9;
            int ks = rest & 7; rest >>= 3;
            int mt = rest & 15; int l = rest >> 4;
            int mp = mt * 16 + (lane & 15);
            int orow = (mp >> 1) + (mp & 1) * 128;
            int k = ks * 32 + (lane >> 4) * 8 + j;
            int tap = k >> 7, c = k & 127;
            cw[i] = (_Float16)conv_w[(((size_t)l * 256 + orow) * 128 + c) * 2 + tap];
        } else if (i < ncw + nrs) {
            i -= ncw;
            int j = i & 7, lane = (i >> 3) & 63, rest = i >> 9;
            int ks = rest & 3; rest >>= 2;
            int mt = rest & 7; int l = rest >> 3;
            int m = mt * 16 + (lane & 15);
            int k = ks * 32 + (lane >> 4) * 8 + j;
            rsw[i] = (_Float16)res_w[((size_t)l * 128 + m) * 128 + k];
        } else if (i < ncw + nrs + nsk) {
            i -= ncw + nrs;
            int j = i & 7, lane = (i >> 3) & 63, rest = i >> 9;
            int ks = rest & 3; rest >>= 2;
            int mt = rest & 15; int l = rest >> 4;
            int m = mt * 16 + (lane & 15);
            int k = ks * 32 + (lane >> 4) * 8 + j;
            skw[i] = (_Float16)skip_w[((size_t)l * 256 + m) * 128 + k];
        } else if (i < ncw + nrs + nsk + nab) {
            i -= ncw + nrs + nsk;
            int j = i & 7, lane = (i >> 3) & 63, rest = i >> 9;
            int ks = rest & 7; int mt = rest >> 3;
            aw[i] = (_Float16)a_w[(mt * 16 + (lane & 15)) * 256 + ks * 32 + (lane >> 4) * 8 + j];
        } else if (i < ncw + nrs + nsk + 2 * nab) {
            i -= ncw + nrs + nsk + nab;
            int j = i & 7, lane = (i >> 3) & 63, rest = i >> 9;
            int ks = rest & 7; int mt = rest >> 3;
            bw[i] = (_Float16)b_w[(mt * 16 + (lane & 15)) * 256 + ks * 32 + (lane >> 4) * 8 + j];
        } else if (i < ncw + nrs + nsk + 2 * nab + ncb) {
            i -= ncw + nrs + nsk + 2 * nab;
            int mp = i & 255; int l = i >> 8;
            cbp[i] = conv_b[l * 256 + (mp >> 1) + (mp & 1) * 128];
        } else {
            i -= ncw + nrs + nsk + 2 * nab + ncb;
            float s = 0.f;
            for (int l = 0; l < NLAYERS; ++l) s += skip_b[l * 256 + i];
            ssum[i] = s;
        }
    }
}

// ---------------- front: h0 (f16, [n][t][c]) ----------------
__global__ void front_kernel(const float* __restrict__ x,
                             const float* __restrict__ w_shift,
                             const float* __restrict__ b_shift,
                             _Float16* __restrict__ h) {
    const int n = blockIdx.y;
    const int t = blockIdx.x * 256 + threadIdx.x;
    float x1 = (t >= 1) ? x[n * WLEN + t - 1] : 0.0f;
    float x2 = (t >= 2) ? x[n * WLEN + t - 2] : 0.0f;
    _Float16* hq = h + ((size_t)n * WLEN + t) * 128;
    #pragma unroll
    for (int c0 = 0; c0 < 128; c0 += 8) {
        half8 v;
        #pragma unroll
        for (int j = 0; j < 8; ++j) {
            int c = c0 + j;
            v[j] = (_Float16)fmaf(w_shift[2 * c], x2,
                                  fmaf(w_shift[2 * c + 1], x1, b_shift[c]));
        }
        *(half8*)&hq[c0] = v;
    }
}

// ---------------- one residual layer (conv + GLU + skip-RMW + res) ----------------
template <bool FIRST>
__global__ __launch_bounds__(256, 2) void layer_kernel(
    const _Float16* __restrict__ h_in, _Float16* __restrict__ h_out,
    _Float16* __restrict__ chunk,
    const _Float16* __restrict__ cw, const float* __restrict__ cb,
    const _Float16* __restrict__ rsw, const float* __restrict__ rb,
    const _Float16* __restrict__ skw, const float* __restrict__ ssum, int d) {
    __shared__ _Float16 SMEM[TT * XROW + TT * GROW];  // 33792 + 17408 = 51200 B
    _Float16* X = SMEM;            // X[t][k], k = tap*128 + c
    _Float16* G = SMEM + TT * XROW;  // G[t][r], gated
    const int n = blockIdx.y, tb = blockIdx.x, t0 = tb * TT;
    const int tid = threadIdx.x;
    const int wave = __builtin_amdgcn_readfirstlane(tid >> 6);
    const int lane = tid & 63, q = lane >> 4, ml = lane & 15;

    // ---- stage both taps: contiguous 16B row-segment copies
    const _Float16* hn = h_in + (size_t)n * WLEN * 128;
    #pragma unroll
    for (int it = 0; it < 8; ++it) {
        int idx = it * 256 + tid;        // 0..2047
        int seg = idx & 15;              // 16B segment (8 f16)
        int rowc = (idx >> 4) & 63;      // dest row (t within tile)
        int tap = idx >> 10;             // 0: t-d, 1: t
        int src_t = t0 + rowc - (tap ? 0 : d);
        half8 v = (half8)(_Float16)0.0f;
        if (src_t >= 0)
            v = *(const half8*)&hn[(size_t)src_t * 128 + seg * 8];
        *(half8*)&X[rowc * XROW + tap * 128 + seg * 8] = v;
    }
    __syncthreads();

    // ---- conv GEMM (interleaved rows): D[m'][t], K=256
    floatx4 acc[4][4];
    #pragma unroll
    for (int mt = 0; mt < 4; ++mt)
        #pragma unroll
        for (int r = 0; r < 4; ++r) {
            float bias = cb[64 * wave + mt * 16 + q * 4 + r];
            #pragma unroll
            for (int nt = 0; nt < 4; ++nt) acc[mt][nt][r] = bias;
        }
    for (int ks = 0; ks < 8; ++ks) {
        half8 b[4];
        #pragma unroll
        for (int nt = 0; nt < 4; ++nt)
            b[nt] = *(const half8*)&X[(nt * 16 + ml) * XROW + ks * 32 + q * 8];
        #pragma unroll
        for (int mt = 0; mt < 4; ++mt) {
            half8 a = *(const half8*)&cw[((((4 * wave + mt) * 8) + ks) * 64 + lane) * 8];
            #pragma unroll
            for (int nt = 0; nt < 4; ++nt)
                acc[mt][nt] = __builtin_amdgcn_mfma_f32_16x16x32_f16(a, b[nt], acc[mt][nt], 0, 0, 0);
        }
    }

    // ---- GLU in registers -> G[t][r] (X untouched; residual taps preserved)
    #pragma unroll
    for (int mt = 0; mt < 4; ++mt)
        #pragma unroll
        for (int nt = 0; nt < 4; ++nt) {
            float g0 = acc[mt][nt][0] * sigmoidf_(acc[mt][nt][1]);
            float g1 = acc[mt][nt][2] * sigmoidf_(acc[mt][nt][3]);
            _Float16 p[2] = {(_Float16)g0, (_Float16)g1};
            *(uint32_t*)&G[(nt * 16 + ml) * GROW + 32 * wave + mt * 8 + 2 * q] = *(uint32_t*)p;
        }
    __syncthreads();

    // ---- skip GEMM (M=256, wave owns mtiles 4w..4w+3) + f16 frag-linear RMW
    {
        floatx4 sacc[4][4];
        #pragma unroll
        for (int mt = 0; mt < 4; ++mt)
            #pragma unroll
            for (int r = 0; r < 4; ++r) {
                float bias = FIRST ? ssum[64 * wave + mt * 16 + q * 4 + r] : 0.0f;
                #pragma unroll
                for (int nt = 0; nt < 4; ++nt) sacc[mt][nt][r] = bias;
            }
        #pragma unroll
        for (int ks = 0; ks < 4; ++ks) {
            half8 b[4];
            #pragma unroll
            for (int nt = 0; nt < 4; ++nt)
                b[nt] = *(const half8*)&G[(nt * 16 + ml) * GROW + ks * 32 + q * 8];
            #pragma unroll
            for (int mt = 0; mt < 4; ++mt) {
                half8 a = *(const half8*)&skw[((((4 * wave + mt) * 4) + ks) * 64 + lane) * 8];
                #pragma unroll
                for (int nt = 0; nt < 4; ++nt)
                    sacc[mt][nt] = __builtin_amdgcn_mfma_f32_16x16x32_f16(a, b[nt], sacc[mt][nt], 0, 0, 0);
            }
        }
        _Float16* cp = chunk + ((size_t)n * NTB + tb) * 16384;
        #pragma unroll
        for (int mt = 0; mt < 4; ++mt)
            #pragma unroll
            for (int nt = 0; nt < 4; ++nt) {
                size_t o = (size_t)((((wave * 4 + mt) * 4) + nt) * 64 + lane) * 4;
                if (FIRST) {
                    half4 v;
                    #pragma unroll
                    for (int r = 0; r < 4; ++r) v[r] = (_Float16)sacc[mt][nt][r];
                    *(half4*)&cp[o] = v;
                } else {
                    half4 v = *(const half4*)&cp[o];
                    half4 w;
                    #pragma unroll
                    for (int r = 0; r < 4; ++r)
                        w[r] = (_Float16)(sacc[mt][nt][r] + (float)v[r]);
                    *(half4*)&cp[o] = w;
                }
            }
    }

    // ---- res GEMM (M=128, wave owns mtiles 2w,2w+1) + residual add
    {
        floatx4 racc[2][4];
        #pragma unroll
        for (int mt = 0; mt < 2; ++mt)
            #pragma unroll
            for (int r = 0; r < 4; ++r) {
                float bias = rb[32 * wave + mt * 16 + q * 4 + r];
                #pragma unroll
                for (int nt = 0; nt < 4; ++nt) racc[mt][nt][r] = bias;
            }
        #pragma unroll
        for (int ks = 0; ks < 4; ++ks) {
            half8 b[4];
            #pragma unroll
            for (int nt = 0; nt < 4; ++nt)
                b[nt] = *(const half8*)&G[(nt * 16 + ml) * GROW + ks * 32 + q * 8];
            #pragma unroll
            for (int mt = 0; mt < 2; ++mt) {
                half8 a = *(const half8*)&rsw[((((2 * wave + mt) * 4) + ks) * 64 + lane) * 8];
                #pragma unroll
                for (int nt = 0; nt < 4; ++nt)
                    racc[mt][nt] = __builtin_amdgcn_mfma_f32_16x16x32_f16(a, b[nt], racc[mt][nt], 0, 0, 0);
            }
        }
        _Float16* ho = h_out + (size_t)n * WLEN * 128;
        #pragma unroll
        for (int mt = 0; mt < 2; ++mt)
            #pragma unroll
            for (int nt = 0; nt < 4; ++nt) {
                int tt = nt * 16 + ml;
                int c = 32 * wave + mt * 16 + q * 4;
                half4 hv = *(const half4*)&X[tt * XROW + 128 + c];  // tap1 = h_in(c,t)
                half4 o;
                #pragma unroll
                for (int r = 0; r < 4; ++r)
                    o[r] = (_Float16)(racc[mt][nt][r] + (float)hv[r]);
                *(half4*)&ho[(size_t)(t0 + tt) * 128 + c] = o;
            }
    }
}

// ---------------- head: chunk -> relu -> a_w -> relu -> b_w -> logits ----------------
__global__ __launch_bounds__(256, 4) void head_kernel(
    float* __restrict__ out, const _Float16* __restrict__ chunk,
    const _Float16* __restrict__ aw, const float* __restrict__ ab,
    const _Float16* __restrict__ bw, const float* __restrict__ bb) {
    __shared__ _Float16 X[TT * XROW];
    const int n = blockIdx.y, tb = blockIdx.x, t0 = tb * TT;
    const int tid = threadIdx.x;
    const int wave = __builtin_amdgcn_readfirstlane(tid >> 6);
    const int lane = tid & 63, q = lane >> 4, ml = lane & 15;

    // ---- z = relu(skips) from frag-linear chunk -> X[t][s]
    {
        const _Float16* cp = chunk + ((size_t)n * NTB + tb) * 16384;
        #pragma unroll
        for (int mt = 0; mt < 4; ++mt)
            #pragma unroll
            for (int nt = 0; nt < 4; ++nt) {
                size_t o = (size_t)((((wave * 4 + mt) * 4) + nt) * 64 + lane) * 4;
                half4 v = *(const half4*)&cp[o];
                half4 z;
                #pragma unroll
                for (int r = 0; r < 4; ++r)
                    z[r] = (_Float16)fmaxf((float)v[r], 0.0f);
                *(half4*)&X[(nt * 16 + ml) * XROW + 64 * wave + mt * 16 + q * 4] = z;
            }
    }
    __syncthreads();

    floatx4 acc[4][4];
    // ---- z2 = relu(a_w @ z + a_b)
    #pragma unroll
    for (int mt = 0; mt < 4; ++mt)
        #pragma unroll
        for (int r = 0; r < 4; ++r) {
            float bias = ab[64 * wave + mt * 16 + q * 4 + r];
            #pragma unroll
            for (int nt = 0; nt < 4; ++nt) acc[mt][nt][r] = bias;
        }
    for (int ks = 0; ks < 8; ++ks) {
        half8 b[4];
        #pragma unroll
        for (int nt = 0; nt < 4; ++nt)
            b[nt] = *(const half8*)&X[(nt * 16 + ml) * XROW + ks * 32 + q * 8];
        #pragma unroll
        for (int mt = 0; mt < 4; ++mt) {
            half8 a = *(const half8*)&aw[((((4 * wave + mt) * 8) + ks) * 64 + lane) * 8];
            #pragma unroll
            for (int nt = 0; nt < 4; ++nt)
                acc[mt][nt] = __builtin_amdgcn_mfma_f32_16x16x32_f16(a, b[nt], acc[mt][nt], 0, 0, 0);
        }
    }
    __syncthreads();
    #pragma unroll
    for (int mt = 0; mt < 4; ++mt)
        #pragma unroll
        for (int nt = 0; nt < 4; ++nt) {
            half4 z;
            #pragma unroll
            for (int r = 0; r < 4; ++r)
                z[r] = (_Float16)fmaxf(acc[mt][nt][r], 0.0f);
            *(half4*)&X[(nt * 16 + ml) * XROW + 64 * wave + mt * 16 + q * 4] = z;
        }
    __syncthreads();

    // ---- logits = b_w @ z2 + b_b
    #pragma unroll
    for (int mt = 0; mt < 4; ++mt)
        #pragma unroll
        for (int r = 0; r < 4; ++r) {
            float bias = bb[64 * wave + mt * 16 + q * 4 + r];
            #pragma unroll
            for (int nt = 0; nt < 4; ++nt) acc[mt][nt][r] = bias;
        }
    for (int ks = 0; ks < 8; ++ks) {
        half8 b[4];
        #pragma unroll
        for (int nt = 0; nt < 4; ++nt)
            b[nt] = *(const half8*)&X[(nt * 16 + ml) * XROW + ks * 32 + q * 8];
        #pragma unroll
        for (int mt = 0; mt < 4; ++mt) {
            half8 a = *(const half8*)&bw[((((4 * wave + mt) * 8) + ks) * 64 + lane) * 8];
            #pragma unroll
            for (int nt = 0; nt < 4; ++nt)
                acc[mt][nt] = __builtin_amdgcn_mfma_f32_16x16x32_f16(a, b[nt], acc[mt][nt], 0, 0, 0);
        }
    }
    float* on = out + (size_t)n * S * WLEN;
    #pragma unroll
    for (int mt = 0; mt < 4; ++mt)
        #pragma unroll
        for (int nt = 0; nt < 4; ++nt)
            #pragma unroll
            for (int r = 0; r < 4; ++r) {
                int o = 64 * wave + mt * 16 + q * 4 + r;
                int tt = t0 + nt * 16 + ml;
                on[(size_t)o * WLEN + tt] = acc[mt][nt][r];
            }
}

extern "C" void kernel_launch(void* const* d_in, const int* in_sizes, int n_in,
                              void* d_out, int out_size, void* d_ws, size_t ws_size,
                              hipStream_t stream) {
    (void)in_sizes; (void)n_in; (void)out_size; (void)ws_size;
    const float* x       = (const float*)d_in[0];
    const float* w_shift = (const float*)d_in[1];
    const float* b_shift = (const float*)d_in[2];
    const float* conv_w  = (const float*)d_in[3];
    const float* conv_b  = (const float*)d_in[4];
    const float* res_w   = (const float*)d_in[5];
    const float* res_b   = (const float*)d_in[6];
    const float* skip_w  = (const float*)d_in[7];
    const float* skip_b  = (const float*)d_in[8];
    const float* a_w     = (const float*)d_in[9];
    const float* a_b     = (const float*)d_in[10];
    const float* b_w     = (const float*)d_in[11];
    const float* b_b     = (const float*)d_in[12];
    float* out = (float*)d_out;

    char* ws = (char*)d_ws;
    size_t off = 0;
    _Float16* hA    = (_Float16*)(ws + off); off += (size_t)NB * WLEN * 128 * 2;
    _Float16* hB    = (_Float16*)(ws + off); off += (size_t)NB * WLEN * 128 * 2;
    _Float16* chunk = (_Float16*)(ws + off); off += (size_t)NB * NTB * 16384 * 2;
    _Float16* cw  = (_Float16*)(ws + off); off += (size_t)NLAYERS * 256 * 256 * 2;
    _Float16* rsw = (_Float16*)(ws + off); off += (size_t)NLAYERS * 128 * 128 * 2;
    _Float16* skw = (_Float16*)(ws + off); off += (size_t)NLAYERS * 256 * 128 * 2;
    _Float16* aw  = (_Float16*)(ws + off); off += 256 * 256 * 2;
    _Float16* bw  = (_Float16*)(ws + off); off += 256 * 256 * 2;
    float* cbp  = (float*)(ws + off); off += (size_t)NLAYERS * 256 * 4;
    float* ssum = (float*)(ws + off); off += 256 * 4;
    // total ~74.3 MB

    prep_kernel<<<512, 256, 0, stream>>>(conv_w, res_w, skip_w, a_w, b_w,
                                         conv_b, skip_b,
                                         cw, rsw, skw, aw, bw, cbp, ssum);
    front_kernel<<<dim3(WLEN / 256, NB), 256, 0, stream>>>(x, w_shift, b_shift, hA);

    const dim3 grid(NTB, NB);
    _Float16* hin = hA;
    _Float16* hout = hB;
    for (int l = 0; l < NLAYERS; ++l) {
        int dil = 1 << (l % 10);
        const _Float16* cwp = cw + (size_t)l * 65536;
        const _Float16* rsp = rsw + (size_t)l * 16384;
        const _Float16* skp = skw + (size_t)l * 32768;
        if (l == 0)
            layer_kernel<true><<<grid, 256, 0, stream>>>(
                hin, hout, chunk, cwp, cbp + l * 256,
                rsp, res_b + l * 128, skp, ssum, dil);
        else
            layer_kernel<false><<<grid, 256, 0, stream>>>(
                hin, hout, chunk, cwp, cbp + l * 256,
                rsp, res_b + l * 128, skp, ssum, dil);
        _Float16* tmp = hin; hin = hout; hout = tmp;
    }

    head_kernel<<<grid, 256, 0, stream>>>(out, chunk, aw, a_b, bw, b_b);
}